// Round 1
// baseline (483.884 us; speedup 1.0000x reference)
//
#include <hip/hip_runtime.h>
#include <math.h>

namespace {
constexpr int kN    = 8192;
constexpr int kC    = 256;
constexpr int kH    = 8;
constexpr int kCH   = 32;
constexpr int kM    = 32;
constexpr int kHID  = 512;
constexpr int kTAB  = 3025;
constexpr int kRowsTotal = 2 * kN;  // B*N = 16384
}

// ---------------- LayerNorm: one row (256 elems) per 256-thread block ----------
__global__ __launch_bounds__(256) void ln_kernel(const float* __restrict__ x,
                                                 const float* __restrict__ w,
                                                 const float* __restrict__ b,
                                                 float* __restrict__ o) {
  int row = blockIdx.x;
  int t = threadIdx.x;
  float v = x[(size_t)row * kC + t];
  float s = v, s2 = v * v;
#pragma unroll
  for (int off = 32; off > 0; off >>= 1) {
    s  += __shfl_down(s, off, 64);
    s2 += __shfl_down(s2, off, 64);
  }
  __shared__ float rs[4], rs2[4];
  __shared__ float mu_s, rstd_s;
  if ((t & 63) == 0) { rs[t >> 6] = s; rs2[t >> 6] = s2; }
  __syncthreads();
  if (t == 0) {
    float tot  = rs[0] + rs[1] + rs[2] + rs[3];
    float tot2 = rs2[0] + rs2[1] + rs2[2] + rs2[3];
    float mu  = tot * (1.0f / kC);
    float var = tot2 * (1.0f / kC) - mu * mu;
    mu_s = mu;
    rstd_s = rsqrtf(var + 1e-5f);
  }
  __syncthreads();
  o[(size_t)row * kC + t] = (v - mu_s) * rstd_s * w[t] + b[t];
}

// ---------------- PE table: pe_full[r][h] = pre_table[r] . pe_w[h] + pe_b[h] ---
__global__ __launch_bounds__(256) void pe_kernel(const float* __restrict__ tab,
                                                 const float* __restrict__ pw,
                                                 const float* __restrict__ pb,
                                                 float* __restrict__ outp) {
  int i = blockIdx.x * 256 + threadIdx.x;
  if (i >= kTAB * kH) return;
  int r = i >> 3, h = i & 7;
  float acc = pb[h];
#pragma unroll
  for (int f = 0; f < 5; ++f) acc += tab[r * 5 + f] * pw[h * 5 + f];
  outp[i] = acc;
}

// ---------------- Generic f32 GEMM: out = epi(A[M,K] @ W[N,K]^T + bias) --------
// 128x128 tile, 256 threads, 8x8 per thread, K-tile 8.
// EPI: 0=q (scale), 1=kv split, 2=proj+residual, 3=gelu, 4=fc2+residual
template <int EPI>
__global__ __launch_bounds__(256) void gemm_kernel(
    const float* __restrict__ A, const float* __restrict__ W,
    const float* __restrict__ bias, float* __restrict__ outp,
    float* __restrict__ out2, const float* __restrict__ res,
    int Nn, int K, float scale) {
  __shared__ float As[8][132];
  __shared__ float Bs[8][132];
  int t = threadIdx.x;
  int tx = t & 15, ty = t >> 4;
  int bm = blockIdx.x * 128;
  int bn = blockIdx.y * 128;
  float acc[8][8] = {};

  int lr = t >> 1;            // 0..127
  int lh = (t & 1) * 4;       // 0 or 4

  for (int k0 = 0; k0 < K; k0 += 8) {
    float4 av = *reinterpret_cast<const float4*>(&A[(size_t)(bm + lr) * K + k0 + lh]);
    float4 bv = *reinterpret_cast<const float4*>(&W[(size_t)(bn + lr) * K + k0 + lh]);
    As[lh + 0][lr] = av.x; As[lh + 1][lr] = av.y; As[lh + 2][lr] = av.z; As[lh + 3][lr] = av.w;
    Bs[lh + 0][lr] = bv.x; Bs[lh + 1][lr] = bv.y; Bs[lh + 2][lr] = bv.z; Bs[lh + 3][lr] = bv.w;
    __syncthreads();
#pragma unroll
    for (int kk = 0; kk < 8; ++kk) {
      float a[8], bb[8];
#pragma unroll
      for (int i = 0; i < 8; ++i) a[i] = As[kk][ty * 8 + i];
#pragma unroll
      for (int j = 0; j < 8; ++j) bb[j] = Bs[kk][tx * 8 + j];
#pragma unroll
      for (int i = 0; i < 8; ++i)
#pragma unroll
        for (int j = 0; j < 8; ++j) acc[i][j] += a[i] * bb[j];
    }
    __syncthreads();
  }

#pragma unroll
  for (int i = 0; i < 8; ++i) {
    int r = bm + ty * 8 + i;
#pragma unroll
    for (int j = 0; j < 8; ++j) {
      int c = bn + tx * 8 + j;
      float v = acc[i][j] + bias[c];
      if constexpr (EPI == 0) {            // q: scale, ld=256
        outp[(size_t)r * 256 + c] = v * scale;
      } else if constexpr (EPI == 1) {     // kv: c = h*64 + s*32 + cc
        int h = c >> 6, sbit = (c >> 5) & 1, cc = c & 31;
        float* dst = sbit ? out2 : outp;
        dst[(size_t)r * 256 + h * 32 + cc] = v;
      } else if constexpr (EPI == 2) {     // proj + residual(feat)
        outp[(size_t)r * 256 + c] = res[(size_t)r * 256 + c] + v;
      } else if constexpr (EPI == 3) {     // fc1 + exact gelu, ld=512
        outp[(size_t)r * 512 + c] = 0.5f * v * (1.0f + erff(v * 0.70710678118654752f));
      } else {                             // fc2 + residual(x)
        outp[(size_t)r * 256 + c] = res[(size_t)r * 256 + c] + v;
      }
    }
  }
}

// ---------------- Attention: one token per 256-thread block --------------------
__global__ __launch_bounds__(256) void attn_kernel(
    const float* __restrict__ q, const float* __restrict__ k,
    const float* __restrict__ v, const int* __restrict__ member_idx,
    const int* __restrict__ pe_idx, const float* __restrict__ cmask,
    const float* __restrict__ pe_full, const float* __restrict__ blank_k,
    const float* __restrict__ blank_v, float* __restrict__ outp) {
  int row = blockIdx.x;        // b*N + n
  int b = row >> 13;           // N = 8192
  int t = threadIdx.x;

  __shared__ float qs[kC];
  __shared__ float kvs[kM][kC + 1];   // +1 pad: banks (m + c) % 32
  __shared__ float logit[kH][kM + 1];
  __shared__ int idxs[kM];

  if (t < kM) idxs[t] = member_idx[(size_t)row * kM + t];
  qs[t] = q[(size_t)row * kC + t];
  __syncthreads();

  // gather K rows (coalesced 1KB per row)
  for (int m = 0; m < kM; ++m)
    kvs[m][t] = k[((size_t)(b * kN + idxs[m])) * kC + t];
  __syncthreads();

  // logits: thread (h = t>>5, m = t&31)
  {
    int h = t >> 5, m = t & 31;
    float acc = 0.f;
#pragma unroll
    for (int c = 0; c < kCH; ++c) acc += qs[h * kCH + c] * kvs[m][h * kCH + c];
    acc += pe_full[(size_t)pe_idx[(size_t)row * kM + m] * kH + h];
    acc += (1.0f - cmask[(size_t)row * kM + m]) * -100.0f;
    logit[h][m] = acc;
  }
  if (t < kH) {
    float acc = 0.f;
#pragma unroll
    for (int c = 0; c < kCH; ++c) acc += qs[t * kCH + c] * blank_k[t * kCH + c];
    logit[t][kM] = fminf(fmaxf(acc, -5.0f), 5.0f);
  }
  __syncthreads();

  // softmax over M+1, one thread per head
  if (t < kH) {
    float mx = -1e30f;
    for (int m = 0; m <= kM; ++m) mx = fmaxf(mx, logit[t][m]);
    float s = 0.f;
    for (int m = 0; m <= kM; ++m) {
      float e = expf(logit[t][m] - mx);
      logit[t][m] = e;
      s += e;
    }
    float inv = 1.0f / s;
    for (int m = 0; m <= kM; ++m) logit[t][m] *= inv;
  }
  __syncthreads();

  // gather V rows (reuse LDS)
  for (int m = 0; m < kM; ++m)
    kvs[m][t] = v[((size_t)(b * kN + idxs[m])) * kC + t];
  __syncthreads();

  // PV: thread (h = t>>5, c = t&31) -> element t of the row
  {
    int h = t >> 5, c = t & 31;
    float acc = 0.f;
#pragma unroll
    for (int m = 0; m < kM; ++m) acc += logit[h][m] * kvs[m][h * kCH + c];
    acc += logit[h][kM] * blank_v[h * kCH + c];
    outp[(size_t)row * kC + t] = acc;
  }
}

extern "C" void kernel_launch(void* const* d_in, const int* in_sizes, int n_in,
                              void* d_out, int out_size, void* d_ws, size_t ws_size,
                              hipStream_t stream) {
  const float* feat       = (const float*)d_in[0];
  const int*   member_idx = (const int*)d_in[1];
  const float* cmask      = (const float*)d_in[2];
  const int*   pe_idx     = (const int*)d_in[3];
  const float* pre_table  = (const float*)d_in[5];
  const float* n1w        = (const float*)d_in[6];
  const float* n1b        = (const float*)d_in[7];
  const float* q_w        = (const float*)d_in[8];
  const float* q_b        = (const float*)d_in[9];
  const float* kv_w       = (const float*)d_in[10];
  const float* kv_b       = (const float*)d_in[11];
  const float* blank_k    = (const float*)d_in[12];
  const float* blank_v    = (const float*)d_in[13];
  const float* pe_w       = (const float*)d_in[14];
  const float* pe_b       = (const float*)d_in[15];
  const float* proj_w     = (const float*)d_in[16];
  const float* proj_b     = (const float*)d_in[17];
  const float* n2w        = (const float*)d_in[18];
  const float* n2b        = (const float*)d_in[19];
  const float* fc1_w      = (const float*)d_in[20];
  const float* fc1_b      = (const float*)d_in[21];
  const float* fc2_w      = (const float*)d_in[22];
  const float* fc2_b      = (const float*)d_in[23];

  float* out = (float*)d_out;
  float* ws  = (float*)d_ws;

  // ws layout (floats). Peak need: 48MB + 96.8KB.
  float* q_buf  = ws;               // [0, 4194304)
  float* k_buf  = ws + 4194304;     // [4194304, 8388608)
  float* v_buf  = ws + 8388608;     // [8388608, 12582912)
  float* pe_buf = ws + 12582912;    // 24200 floats
  float* x_buf  = ws;               // alias q_buf (dead after attention)
  float* h1_buf = ws + 4194304;     // alias k,v (dead after attention), 32MB

  // d_out as scratch for x_ln -> attn_out -> y_ln (sequential lifetimes)
  float* xln      = out;
  float* attn_out = out;
  float* yln      = out;

  const float scale = 0.17677669529663687f;  // 32^-0.5

  ln_kernel<<<kRowsTotal, 256, 0, stream>>>(feat, n1w, n1b, xln);
  pe_kernel<<<(kTAB * kH + 255) / 256, 256, 0, stream>>>(pre_table, pe_w, pe_b, pe_buf);
  gemm_kernel<0><<<dim3(kRowsTotal / 128, 2), 256, 0, stream>>>(
      xln, q_w, q_b, q_buf, nullptr, nullptr, 256, 256, scale);
  gemm_kernel<1><<<dim3(kRowsTotal / 128, 4), 256, 0, stream>>>(
      xln, kv_w, kv_b, k_buf, v_buf, nullptr, 512, 256, 0.f);
  attn_kernel<<<kRowsTotal, 256, 0, stream>>>(
      q_buf, k_buf, v_buf, member_idx, pe_idx, cmask, pe_buf, blank_k, blank_v,
      attn_out);
  gemm_kernel<2><<<dim3(kRowsTotal / 128, 2), 256, 0, stream>>>(
      attn_out, proj_w, proj_b, x_buf, nullptr, feat, 256, 256, 0.f);
  ln_kernel<<<kRowsTotal, 256, 0, stream>>>(x_buf, n2w, n2b, yln);
  gemm_kernel<3><<<dim3(kRowsTotal / 128, 4), 256, 0, stream>>>(
      yln, fc1_w, fc1_b, h1_buf, nullptr, nullptr, 512, 256, 0.f);
  gemm_kernel<4><<<dim3(kRowsTotal / 128, 2), 256, 0, stream>>>(
      h1_buf, fc2_w, fc2_b, out, nullptr, x_buf, 256, 512, 0.f);
}

// Round 2
// 190.006 us; speedup vs baseline: 2.5467x; 2.5467x over previous
//
#include <hip/hip_runtime.h>
#include <math.h>

namespace {
constexpr int kN    = 8192;
constexpr int kC    = 256;
constexpr int kM    = 32;
constexpr int kTAB  = 3025;
constexpr int kRowsTotal = 2 * kN;  // B*N = 16384
constexpr float kScale = 0.17677669529663687f;  // 32^-0.5
}

typedef __attribute__((ext_vector_type(8))) short bf16x8;
typedef __attribute__((ext_vector_type(4))) float f32x4;

__device__ __forceinline__ unsigned short f2bf(float f) {
  unsigned int u = __float_as_uint(f);
  u += 0x7fffu + ((u >> 16) & 1u);   // round-to-nearest-even
  return (unsigned short)(u >> 16);
}
__device__ __forceinline__ float bf2f(unsigned short b) {
  return __uint_as_float(((unsigned int)b) << 16);
}

#define GLOAD16(g, l)                                                   \
  __builtin_amdgcn_global_load_lds(                                     \
      (const __attribute__((address_space(1))) void*)(g),               \
      (__attribute__((address_space(3))) void*)(l), 16, 0, 0)

// ---------------- LayerNorm -> bf16 ----------------
__global__ __launch_bounds__(256) void ln_bf16_kernel(
    const float* __restrict__ x, const float* __restrict__ w,
    const float* __restrict__ b, unsigned short* __restrict__ o) {
  int row = blockIdx.x;
  int t = threadIdx.x;
  float v = x[(size_t)row * kC + t];
  float s = v, s2 = v * v;
#pragma unroll
  for (int off = 32; off > 0; off >>= 1) {
    s  += __shfl_down(s, off, 64);
    s2 += __shfl_down(s2, off, 64);
  }
  __shared__ float rs[4], rs2[4];
  __shared__ float mu_s, rstd_s;
  if ((t & 63) == 0) { rs[t >> 6] = s; rs2[t >> 6] = s2; }
  __syncthreads();
  if (t == 0) {
    float tot  = rs[0] + rs[1] + rs[2] + rs[3];
    float tot2 = rs2[0] + rs2[1] + rs2[2] + rs2[3];
    float mu  = tot * (1.0f / kC);
    float var = tot2 * (1.0f / kC) - mu * mu;
    mu_s = mu;
    rstd_s = rsqrtf(var + 1e-5f);
  }
  __syncthreads();
  o[(size_t)row * kC + t] = f2bf((v - mu_s) * rstd_s * w[t] + b[t]);
}

// ---------------- PE table ----------------
__global__ __launch_bounds__(256) void pe_kernel(const float* __restrict__ tab,
                                                 const float* __restrict__ pw,
                                                 const float* __restrict__ pb,
                                                 float* __restrict__ outp) {
  int i = blockIdx.x * 256 + threadIdx.x;
  if (i >= kTAB * 8) return;
  int r = i >> 3, h = i & 7;
  float acc = pb[h];
#pragma unroll
  for (int f = 0; f < 5; ++f) acc += tab[r * 5 + f] * pw[h * 5 + f];
  outp[i] = acc;
}

// ---------------- cast weights to bf16 (+ concat qkv bias) ----------------
__global__ __launch_bounds__(256) void cast_weights_kernel(
    const float* __restrict__ qw, const float* __restrict__ kvw,
    const float* __restrict__ pjw, const float* __restrict__ f1w,
    const float* __restrict__ f2w, const float* __restrict__ qb,
    const float* __restrict__ kvb, unsigned short* __restrict__ wqkv,
    unsigned short* __restrict__ wproj, unsigned short* __restrict__ wfc1,
    unsigned short* __restrict__ wfc2, float* __restrict__ bqkv) {
  int i = blockIdx.x * 256 + threadIdx.x;
  if (i < 65536)       wqkv[i]            = f2bf(qw[i]);
  else if (i < 196608) wqkv[i]            = f2bf(kvw[i - 65536]);
  else if (i < 262144) wproj[i - 196608]  = f2bf(pjw[i - 196608]);
  else if (i < 393216) wfc1[i - 262144]   = f2bf(f1w[i - 262144]);
  else if (i < 524288) wfc2[i - 393216]   = f2bf(f2w[i - 393216]);
  else if (i < 524544) bqkv[i - 524288]   = qb[i - 524288];
  else if (i < 525056) bqkv[i - 524288]   = kvb[i - 524544];
}

// ---------------- bf16 MFMA GEMM: C = A[M,K] @ W[N,K]^T, fused epilogues -----
// 128x128 tile, 256 threads = 4 waves (2x2), each wave 4x4 frags of 16x16x32.
// EPI 0: QKV (col<256 -> q f32 *scale; else split k/v bf16)
// EPI 1: proj + residual -> f32
// EPI 2: fc1 + exact gelu -> bf16
// EPI 3: fc2 + residual -> f32
template <int EPI, int KDIM>
__global__ __launch_bounds__(256) void mfma_gemm(
    const unsigned short* __restrict__ A, const unsigned short* __restrict__ Wt,
    const float* __restrict__ bias, void* __restrict__ o1,
    unsigned short* __restrict__ o2, unsigned short* __restrict__ o3,
    const float* __restrict__ res) {
  __shared__ alignas(16) unsigned short As[128 * 32];
  __shared__ alignas(16) unsigned short Bs[128 * 32];
  int t = threadIdx.x;
  int w = t >> 6, l = t & 63;
  int wr = w >> 1, wc = w & 1;
  int bm = blockIdx.x * 128, bn = blockIdx.y * 128;

  f32x4 acc[4][4] = {};

  // staging: wave w covers row-groups {2w, 2w+1} (16 rows each);
  // lane l -> row g*16 + l/4, 16B chunk l%4.  LDS dest = waveuniform + l*16B.
  const size_t aoff = (size_t)(bm + w * 32 + (l >> 2)) * KDIM + (l & 3) * 8;
  const size_t boff = (size_t)(bn + w * 32 + (l >> 2)) * KDIM + (l & 3) * 8;
  unsigned short* AsW = As + w * 1024 + l * 8;   // g=2w
  unsigned short* BsW = Bs + w * 1024 + l * 8;

  const int lr = l & 15, lk = l >> 4;

  for (int k0 = 0; k0 < KDIM; k0 += 32) {
    GLOAD16(A + aoff + k0, AsW);
    GLOAD16(A + aoff + k0 + (size_t)16 * KDIM, AsW + 512);
    GLOAD16(Wt + boff + k0, BsW);
    GLOAD16(Wt + boff + k0 + (size_t)16 * KDIM, BsW + 512);
    __syncthreads();
    bf16x8 af[4], bf[4];
#pragma unroll
    for (int mi = 0; mi < 4; ++mi)
      af[mi] = *(const bf16x8*)(As + (wr * 64 + mi * 16 + lr) * 32 + lk * 8);
#pragma unroll
    for (int ni = 0; ni < 4; ++ni)
      bf[ni] = *(const bf16x8*)(Bs + (wc * 64 + ni * 16 + lr) * 32 + lk * 8);
#pragma unroll
    for (int mi = 0; mi < 4; ++mi)
#pragma unroll
      for (int ni = 0; ni < 4; ++ni)
        acc[mi][ni] = __builtin_amdgcn_mfma_f32_16x16x32_bf16(
            af[mi], bf[ni], acc[mi][ni], 0, 0, 0);
    __syncthreads();
  }

  // epilogue: C/D layout col=lane&15, row=(lane>>4)*4+j
#pragma unroll
  for (int mi = 0; mi < 4; ++mi) {
#pragma unroll
    for (int ni = 0; ni < 4; ++ni) {
      int row0 = bm + wr * 64 + mi * 16 + lk * 4;
      int col  = bn + wc * 64 + ni * 16 + lr;
      float bv = bias[col];
#pragma unroll
      for (int j = 0; j < 4; ++j) {
        int r = row0 + j;
        float x = acc[mi][ni][j] + bv;
        if constexpr (EPI == 0) {
          if (col < 256) {
            ((float*)o1)[(size_t)r * 256 + col] = x * kScale;
          } else {
            int c = col - 256;
            int h = c >> 6, sbit = (c >> 5) & 1, ch = c & 31;
            unsigned short* dst = sbit ? o3 : o2;
            dst[(size_t)r * 256 + h * 32 + ch] = f2bf(x);
          }
        } else if constexpr (EPI == 1) {
          ((float*)o1)[(size_t)r * 256 + col] = res[(size_t)r * 256 + col] + x;
        } else if constexpr (EPI == 2) {
          float g = 0.5f * x * (1.0f + erff(x * 0.70710678118654752f));
          ((unsigned short*)o1)[(size_t)r * 512 + col] = f2bf(g);
        } else {
          ((float*)o1)[(size_t)r * 256 + col] = res[(size_t)r * 256 + col] + x;
        }
      }
    }
  }
}

// ---------------- Attention: one token per 256-thread block ----------------
__global__ __launch_bounds__(256) void attn_kernel(
    const float* __restrict__ q, const unsigned short* __restrict__ k,
    const unsigned short* __restrict__ v, const int* __restrict__ member_idx,
    const int* __restrict__ pe_idx, const float* __restrict__ cmask,
    const float* __restrict__ pe_full, const float* __restrict__ blank_k,
    const float* __restrict__ blank_v, unsigned short* __restrict__ outp) {
  int row = blockIdx.x;        // b*N + n
  int b = row >> 13;           // N = 8192
  int t = threadIdx.x;

  __shared__ float qs[256];
  __shared__ unsigned int kvu[32][129];   // 2 bf16 per uint, +1 pad kills col conflicts
  __shared__ float logit[8][33];
  __shared__ int idxs[32];

  if (t < 32) idxs[t] = member_idx[(size_t)row * 32 + t];
  qs[t] = q[(size_t)row * 256 + t];
  __syncthreads();

  // gather K rows: 2 rows per iter, 128 threads per row (uint = 2 bf16)
  {
    int half = t >> 7, c2 = t & 127;
#pragma unroll
    for (int m0 = 0; m0 < 32; m0 += 2) {
      int m = m0 + half;
      kvu[m][c2] =
          *(const unsigned int*)(k + ((size_t)(b * kN + idxs[m])) * 256 + c2 * 2);
    }
  }
  __syncthreads();

  int h = t >> 5, m = t & 31;
  {
    float acc = 0.f;
    const unsigned int* kr = kvu[m];
#pragma unroll
    for (int cc = 0; cc < 16; ++cc) {
      unsigned int u = kr[h * 16 + cc];
      acc += qs[h * 32 + 2 * cc]     * __uint_as_float(u << 16);
      acc += qs[h * 32 + 2 * cc + 1] * __uint_as_float(u & 0xffff0000u);
    }
    acc += pe_full[(size_t)pe_idx[(size_t)row * 32 + m] * 8 + h];
    acc += (1.0f - cmask[(size_t)row * 32 + m]) * -100.0f;
    logit[h][m] = acc;
  }
  if (t < 8) {
    float acc = 0.f;
#pragma unroll
    for (int c = 0; c < 32; ++c) acc += qs[t * 32 + c] * blank_k[t * 32 + c];
    logit[t][32] = fminf(fmaxf(acc, -5.0f), 5.0f);
  }
  __syncthreads();

  if (t < 8) {
    float mx = logit[t][0];
    for (int i = 1; i < 33; ++i) mx = fmaxf(mx, logit[t][i]);
    float s = 0.f;
    for (int i = 0; i < 33; ++i) {
      float e = expf(logit[t][i] - mx);
      logit[t][i] = e;
      s += e;
    }
    float inv = 1.0f / s;
    for (int i = 0; i < 33; ++i) logit[t][i] *= inv;
  }
  __syncthreads();

  // gather V rows (reuse kvu)
  {
    int half = t >> 7, c2 = t & 127;
#pragma unroll
    for (int m0 = 0; m0 < 32; m0 += 2) {
      int mm = m0 + half;
      kvu[mm][c2] =
          *(const unsigned int*)(v + ((size_t)(b * kN + idxs[mm])) * 256 + c2 * 2);
    }
  }
  __syncthreads();

  // PV: thread t -> (h = t>>5, ch = t&31)
  {
    int ch = t & 31;
    float acc = 0.f;
#pragma unroll
    for (int mm = 0; mm < 32; ++mm) {
      unsigned int u = kvu[mm][h * 16 + (ch >> 1)];
      float vv = (ch & 1) ? __uint_as_float(u & 0xffff0000u)
                          : __uint_as_float(u << 16);
      acc += logit[h][mm] * vv;
    }
    acc += logit[h][32] * blank_v[h * 32 + ch];
    outp[(size_t)row * 256 + t] = f2bf(acc);
  }
}

extern "C" void kernel_launch(void* const* d_in, const int* in_sizes, int n_in,
                              void* d_out, int out_size, void* d_ws, size_t ws_size,
                              hipStream_t stream) {
  const float* feat       = (const float*)d_in[0];
  const int*   member_idx = (const int*)d_in[1];
  const float* cmask      = (const float*)d_in[2];
  const int*   pe_idx     = (const int*)d_in[3];
  const float* pre_table  = (const float*)d_in[5];
  const float* n1w        = (const float*)d_in[6];
  const float* n1b        = (const float*)d_in[7];
  const float* q_w        = (const float*)d_in[8];
  const float* q_b        = (const float*)d_in[9];
  const float* kv_w       = (const float*)d_in[10];
  const float* kv_b       = (const float*)d_in[11];
  const float* blank_k    = (const float*)d_in[12];
  const float* blank_v    = (const float*)d_in[13];
  const float* pe_w       = (const float*)d_in[14];
  const float* pe_b       = (const float*)d_in[15];
  const float* proj_w     = (const float*)d_in[16];
  const float* proj_b     = (const float*)d_in[17];
  const float* n2w        = (const float*)d_in[18];
  const float* n2b        = (const float*)d_in[19];
  const float* fc1_w      = (const float*)d_in[20];
  const float* fc1_b      = (const float*)d_in[21];
  const float* fc2_w      = (const float*)d_in[22];
  const float* fc2_b      = (const float*)d_in[23];

  float* out = (float*)d_out;
  unsigned char* ws = (unsigned char*)d_ws;

  // ws layout (bytes)
  unsigned short* xln   = (unsigned short*)(ws + 0);           // 8 MB, later attn_out
  float*          q_buf = (float*)(ws + 8388608);              // 16 MB, later yln
  unsigned short* k_buf = (unsigned short*)(ws + 25165824);    // 8 MB \ later h1 (16MB)
  unsigned short* v_buf = (unsigned short*)(ws + 33554432);    // 8 MB /
  unsigned short* wqkv  = (unsigned short*)(ws + 41943040);    // 384 KB
  unsigned short* wproj = (unsigned short*)(ws + 42336256);    // 128 KB
  unsigned short* wfc1  = (unsigned short*)(ws + 42467328);    // 256 KB
  unsigned short* wfc2  = (unsigned short*)(ws + 42729472);    // 256 KB
  float*          bqkv  = (float*)(ws + 42991616);             // 3 KB
  float*          pe_buf= (float*)(ws + 42994688);             // ~97 KB
  unsigned short* attn_out = xln;                               // alias
  unsigned short* yln   = (unsigned short*)q_buf;               // alias
  unsigned short* h1    = k_buf;                                // alias k+v (16MB)

  cast_weights_kernel<<<2052, 256, 0, stream>>>(
      q_w, kv_w, proj_w, fc1_w, fc2_w, q_b, kv_b, wqkv, wproj, wfc1, wfc2, bqkv);
  pe_kernel<<<(kTAB * 8 + 255) / 256, 256, 0, stream>>>(pre_table, pe_w, pe_b, pe_buf);
  ln_bf16_kernel<<<kRowsTotal, 256, 0, stream>>>(feat, n1w, n1b, xln);

  // fused QKV: [16384 x 768] = xln @ wqkv^T
  mfma_gemm<0, 256><<<dim3(kRowsTotal / 128, 6), 256, 0, stream>>>(
      xln, wqkv, bqkv, q_buf, k_buf, v_buf, nullptr);

  attn_kernel<<<kRowsTotal, 256, 0, stream>>>(
      q_buf, k_buf, v_buf, member_idx, pe_idx, cmask, pe_buf, blank_k, blank_v,
      attn_out);

  // proj + residual -> x (f32, in d_out)
  mfma_gemm<1, 256><<<dim3(kRowsTotal / 128, 2), 256, 0, stream>>>(
      attn_out, wproj, proj_b, out, nullptr, nullptr, feat);

  ln_bf16_kernel<<<kRowsTotal, 256, 0, stream>>>(out, n2w, n2b, yln);

  // fc1 + gelu -> h1 (bf16)
  mfma_gemm<2, 256><<<dim3(kRowsTotal / 128, 4), 256, 0, stream>>>(
      yln, wfc1, fc1_b, h1, nullptr, nullptr, nullptr);

  // fc2 + residual(x) -> out (f32, in-place over d_out)
  mfma_gemm<3, 512><<<dim3(kRowsTotal / 128, 2), 256, 0, stream>>>(
      h1, wfc2, fc2_b, out, nullptr, nullptr, out);
}

// Round 3
// 170.234 us; speedup vs baseline: 2.8425x; 1.1161x over previous
//
#include <hip/hip_runtime.h>
#include <math.h>

namespace {
constexpr int kN    = 8192;
constexpr int kC    = 256;
constexpr int kM    = 32;
constexpr int kTAB  = 3025;
constexpr int kRowsTotal = 2 * kN;  // B*N = 16384
constexpr float kScale = 0.17677669529663687f;  // 32^-0.5
}

typedef __attribute__((ext_vector_type(8))) short bf16x8;
typedef __attribute__((ext_vector_type(4))) float f32x4;

__device__ __forceinline__ unsigned short f2bf(float f) {
  unsigned int u = __float_as_uint(f);
  u += 0x7fffu + ((u >> 16) & 1u);   // round-to-nearest-even
  return (unsigned short)(u >> 16);
}
__device__ __forceinline__ float bflo(unsigned int u) {
  return __uint_as_float(u << 16);
}
__device__ __forceinline__ float bfhi(unsigned int u) {
  return __uint_as_float(u & 0xffff0000u);
}

#define GLOAD16(g, l)                                                   \
  __builtin_amdgcn_global_load_lds(                                     \
      (const __attribute__((address_space(1))) void*)(g),               \
      (__attribute__((address_space(3))) void*)(l), 16, 0, 0)

// ---------------- LayerNorm -> bf16 ----------------
__global__ __launch_bounds__(256) void ln_bf16_kernel(
    const float* __restrict__ x, const float* __restrict__ w,
    const float* __restrict__ b, unsigned short* __restrict__ o) {
  int row = blockIdx.x;
  int t = threadIdx.x;
  float v = x[(size_t)row * kC + t];
  float s = v, s2 = v * v;
#pragma unroll
  for (int off = 32; off > 0; off >>= 1) {
    s  += __shfl_down(s, off, 64);
    s2 += __shfl_down(s2, off, 64);
  }
  __shared__ float rs[4], rs2[4];
  __shared__ float mu_s, rstd_s;
  if ((t & 63) == 0) { rs[t >> 6] = s; rs2[t >> 6] = s2; }
  __syncthreads();
  if (t == 0) {
    float tot  = rs[0] + rs[1] + rs[2] + rs[3];
    float tot2 = rs2[0] + rs2[1] + rs2[2] + rs2[3];
    float mu  = tot * (1.0f / kC);
    float var = tot2 * (1.0f / kC) - mu * mu;
    mu_s = mu;
    rstd_s = rsqrtf(var + 1e-5f);
  }
  __syncthreads();
  o[(size_t)row * kC + t] = f2bf((v - mu_s) * rstd_s * w[t] + b[t]);
}

// ---------------- PE table ----------------
__global__ __launch_bounds__(256) void pe_kernel(const float* __restrict__ tab,
                                                 const float* __restrict__ pw,
                                                 const float* __restrict__ pb,
                                                 float* __restrict__ outp) {
  int i = blockIdx.x * 256 + threadIdx.x;
  if (i >= kTAB * 8) return;
  int r = i >> 3, h = i & 7;
  float acc = pb[h];
#pragma unroll
  for (int f = 0; f < 5; ++f) acc += tab[r * 5 + f] * pw[h * 5 + f];
  outp[i] = acc;
}

// ---------------- cast weights to bf16 (+ concat qkv bias) ----------------
__global__ __launch_bounds__(256) void cast_weights_kernel(
    const float* __restrict__ qw, const float* __restrict__ kvw,
    const float* __restrict__ pjw, const float* __restrict__ f1w,
    const float* __restrict__ f2w, const float* __restrict__ qb,
    const float* __restrict__ kvb, unsigned short* __restrict__ wqkv,
    unsigned short* __restrict__ wproj, unsigned short* __restrict__ wfc1,
    unsigned short* __restrict__ wfc2, float* __restrict__ bqkv) {
  int i = blockIdx.x * 256 + threadIdx.x;
  if (i < 65536)       wqkv[i]            = f2bf(qw[i]);
  else if (i < 196608) wqkv[i]            = f2bf(kvw[i - 65536]);
  else if (i < 262144) wproj[i - 196608]  = f2bf(pjw[i - 196608]);
  else if (i < 393216) wfc1[i - 262144]   = f2bf(f1w[i - 262144]);
  else if (i < 524288) wfc2[i - 393216]   = f2bf(f2w[i - 393216]);
  else if (i < 524544) bqkv[i - 524288]   = qb[i - 524288];
  else if (i < 525056) bqkv[i - 524288]   = kvb[i - 524544];
}

// ---------------- bf16 MFMA GEMM: C = A[M,K] @ W[N,K]^T, fused epilogues -----
template <int EPI, int KDIM>
__global__ __launch_bounds__(256) void mfma_gemm(
    const unsigned short* __restrict__ A, const unsigned short* __restrict__ Wt,
    const float* __restrict__ bias, void* __restrict__ o1,
    unsigned short* __restrict__ o2, unsigned short* __restrict__ o3,
    const float* __restrict__ res) {
  __shared__ alignas(16) unsigned short As[128 * 32];
  __shared__ alignas(16) unsigned short Bs[128 * 32];
  int t = threadIdx.x;
  int w = t >> 6, l = t & 63;
  int wr = w >> 1, wc = w & 1;
  int bm = blockIdx.x * 128, bn = blockIdx.y * 128;

  f32x4 acc[4][4] = {};

  const size_t aoff = (size_t)(bm + w * 32 + (l >> 2)) * KDIM + (l & 3) * 8;
  const size_t boff = (size_t)(bn + w * 32 + (l >> 2)) * KDIM + (l & 3) * 8;
  unsigned short* AsW = As + w * 1024 + l * 8;
  unsigned short* BsW = Bs + w * 1024 + l * 8;

  const int lr = l & 15, lk = l >> 4;

  for (int k0 = 0; k0 < KDIM; k0 += 32) {
    GLOAD16(A + aoff + k0, AsW);
    GLOAD16(A + aoff + k0 + (size_t)16 * KDIM, AsW + 512);
    GLOAD16(Wt + boff + k0, BsW);
    GLOAD16(Wt + boff + k0 + (size_t)16 * KDIM, BsW + 512);
    __syncthreads();
    bf16x8 af[4], bf[4];
#pragma unroll
    for (int mi = 0; mi < 4; ++mi)
      af[mi] = *(const bf16x8*)(As + (wr * 64 + mi * 16 + lr) * 32 + lk * 8);
#pragma unroll
    for (int ni = 0; ni < 4; ++ni)
      bf[ni] = *(const bf16x8*)(Bs + (wc * 64 + ni * 16 + lr) * 32 + lk * 8);
#pragma unroll
    for (int mi = 0; mi < 4; ++mi)
#pragma unroll
      for (int ni = 0; ni < 4; ++ni)
        acc[mi][ni] = __builtin_amdgcn_mfma_f32_16x16x32_bf16(
            af[mi], bf[ni], acc[mi][ni], 0, 0, 0);
    __syncthreads();
  }

#pragma unroll
  for (int mi = 0; mi < 4; ++mi) {
#pragma unroll
    for (int ni = 0; ni < 4; ++ni) {
      int row0 = bm + wr * 64 + mi * 16 + lk * 4;
      int col  = bn + wc * 64 + ni * 16 + lr;
      float bv = bias[col];
#pragma unroll
      for (int j = 0; j < 4; ++j) {
        int r = row0 + j;
        float x = acc[mi][ni][j] + bv;
        if constexpr (EPI == 0) {
          if (col < 256) {
            ((float*)o1)[(size_t)r * 256 + col] = x * kScale;
          } else {
            int c = col - 256;
            int h = c >> 6, sbit = (c >> 5) & 1, ch = c & 31;
            unsigned short* dst = sbit ? o3 : o2;
            dst[(size_t)r * 256 + h * 32 + ch] = f2bf(x);
          }
        } else if constexpr (EPI == 1) {
          ((float*)o1)[(size_t)r * 256 + col] = res[(size_t)r * 256 + col] + x;
        } else if constexpr (EPI == 2) {
          float g = 0.5f * x * (1.0f + erff(x * 0.70710678118654752f));
          ((unsigned short*)o1)[(size_t)r * 512 + col] = f2bf(g);
        } else {
          ((float*)o1)[(size_t)r * 256 + col] = res[(size_t)r * 256 + col] + x;
        }
      }
    }
  }
}

// ---------------- Attention: one WAVE per token, register gather ----------------
// lane l: h = l>>3 (head), g = l&7. QK: 4 logits per lane (m = g+8*mi).
// PV: 4 output channels per lane (c = g*4..g*4+3) of head h.
__global__ __launch_bounds__(256) void attn_kernel(
    const float* __restrict__ q, const unsigned short* __restrict__ k,
    const unsigned short* __restrict__ v, const int* __restrict__ member_idx,
    const int* __restrict__ pe_idx, const float* __restrict__ cmask,
    const float* __restrict__ pe_full, const float* __restrict__ blank_k,
    const float* __restrict__ blank_v, unsigned short* __restrict__ outp) {
  int t = threadIdx.x;
  int w = t >> 6, l = t & 63;
  int row = blockIdx.x * 4 + w;
  int b = row >> 13;  // N = 8192
  const size_t kvbase = (size_t)b * kN;

  __shared__ float qs[4][8][36];   // [wave][head][ch], pad 36: banks 4h+i*4, free
  __shared__ float aw[4][8][40];   // attn weights, pad 40: 2-way max, free
  __shared__ int   idxs[4][32];
  __shared__ float mkb[4][32];
  __shared__ int   pei[4][32];

  // ---- stage q + indices ----
  {
    float4 qv4 = *(const float4*)(q + (size_t)row * 256 + l * 4);
    *(float4*)&qs[w][l >> 3][(l & 7) * 4] = qv4;
    if (l < 32) {
      idxs[w][l] = member_idx[(size_t)row * 32 + l];
      mkb[w][l]  = (1.0f - cmask[(size_t)row * 32 + l]) * -100.0f;
      pei[w][l]  = pe_idx[(size_t)row * 32 + l];
    }
  }
  __syncthreads();

  const int h = l >> 3, g = l & 7;

  float4 qv[8];
#pragma unroll
  for (int i = 0; i < 8; ++i) qv[i] = *(const float4*)&qs[w][h][i * 4];

  // ---- QK logits: direct global K loads ----
  float lg[4];
#pragma unroll
  for (int mi = 0; mi < 4; ++mi) {
    int m = g + mi * 8;
    int idx = idxs[w][m];
    const unsigned short* kr = k + ((kvbase + idx) * 256 + h * 32);
    float acc = 0.f;
#pragma unroll
    for (int i = 0; i < 8; ++i) {
      uint2 u = *(const uint2*)(kr + i * 4);
      acc = fmaf(qv[i].x, bflo(u.x), acc);
      acc = fmaf(qv[i].y, bfhi(u.x), acc);
      acc = fmaf(qv[i].z, bflo(u.y), acc);
      acc = fmaf(qv[i].w, bfhi(u.y), acc);
    }
    lg[mi] = acc + mkb[w][m] + pe_full[(size_t)pei[w][m] * 8 + h];
  }

  // ---- blank logit (redundant but identical across the 8-lane head group) ----
  float bl = 0.f;
#pragma unroll
  for (int i = 0; i < 8; ++i) {
    float4 bk = *(const float4*)(blank_k + h * 32 + i * 4);
    bl += qv[i].x * bk.x + qv[i].y * bk.y + qv[i].z * bk.z + qv[i].w * bk.w;
  }
  bl = fminf(fmaxf(bl, -5.0f), 5.0f);

  // ---- wave-parallel softmax over 33 (8-lane group reduction) ----
  float mx = fmaxf(fmaxf(lg[0], lg[1]), fmaxf(lg[2], lg[3]));
#pragma unroll
  for (int d = 1; d < 8; d <<= 1) mx = fmaxf(mx, __shfl_xor(mx, d, 64));
  mx = fmaxf(mx, bl);
  float e[4], s = 0.f;
#pragma unroll
  for (int mi = 0; mi < 4; ++mi) { e[mi] = __expf(lg[mi] - mx); s += e[mi]; }
#pragma unroll
  for (int d = 1; d < 8; d <<= 1) s += __shfl_xor(s, d, 64);
  float eb = __expf(bl - mx);
  s += eb;
  float inv = __builtin_amdgcn_rcpf(s);
#pragma unroll
  for (int mi = 0; mi < 4; ++mi) aw[w][h][g + mi * 8] = e[mi] * inv;
  if (g == 0) aw[w][h][32] = eb * inv;
  __syncthreads();

  // ---- PV: direct global V loads, weights broadcast from LDS ----
  const int c0 = g * 4;
  const unsigned short* vbase = v + h * 32 + c0;
  float a0 = 0.f, a1 = 0.f, a2 = 0.f, a3 = 0.f;
#pragma unroll 8
  for (int m = 0; m < 32; ++m) {
    float a = aw[w][h][m];
    int idx = idxs[w][m];
    uint2 u = *(const uint2*)(vbase + (kvbase + idx) * 256);
    a0 = fmaf(a, bflo(u.x), a0);
    a1 = fmaf(a, bfhi(u.x), a1);
    a2 = fmaf(a, bflo(u.y), a2);
    a3 = fmaf(a, bfhi(u.y), a3);
  }
  {
    float ab = aw[w][h][32];
    float4 bv = *(const float4*)(blank_v + h * 32 + c0);
    a0 = fmaf(ab, bv.x, a0);
    a1 = fmaf(ab, bv.y, a1);
    a2 = fmaf(ab, bv.z, a2);
    a3 = fmaf(ab, bv.w, a3);
  }
  uint2 o;
  o.x = ((unsigned int)f2bf(a1) << 16) | f2bf(a0);
  o.y = ((unsigned int)f2bf(a3) << 16) | f2bf(a2);
  *(uint2*)(outp + (size_t)row * 256 + h * 32 + c0) = o;
}

extern "C" void kernel_launch(void* const* d_in, const int* in_sizes, int n_in,
                              void* d_out, int out_size, void* d_ws, size_t ws_size,
                              hipStream_t stream) {
  const float* feat       = (const float*)d_in[0];
  const int*   member_idx = (const int*)d_in[1];
  const float* cmask      = (const float*)d_in[2];
  const int*   pe_idx     = (const int*)d_in[3];
  const float* pre_table  = (const float*)d_in[5];
  const float* n1w        = (const float*)d_in[6];
  const float* n1b        = (const float*)d_in[7];
  const float* q_w        = (const float*)d_in[8];
  const float* q_b        = (const float*)d_in[9];
  const float* kv_w       = (const float*)d_in[10];
  const float* kv_b       = (const float*)d_in[11];
  const float* blank_k    = (const float*)d_in[12];
  const float* blank_v    = (const float*)d_in[13];
  const float* pe_w       = (const float*)d_in[14];
  const float* pe_b       = (const float*)d_in[15];
  const float* proj_w     = (const float*)d_in[16];
  const float* proj_b     = (const float*)d_in[17];
  const float* n2w        = (const float*)d_in[18];
  const float* n2b        = (const float*)d_in[19];
  const float* fc1_w      = (const float*)d_in[20];
  const float* fc1_b      = (const float*)d_in[21];
  const float* fc2_w      = (const float*)d_in[22];
  const float* fc2_b      = (const float*)d_in[23];

  float* out = (float*)d_out;
  unsigned char* ws = (unsigned char*)d_ws;

  unsigned short* xln   = (unsigned short*)(ws + 0);           // 8 MB, later attn_out
  float*          q_buf = (float*)(ws + 8388608);              // 16 MB, later yln
  unsigned short* k_buf = (unsigned short*)(ws + 25165824);    // 8 MB \ later h1 (16MB)
  unsigned short* v_buf = (unsigned short*)(ws + 33554432);    // 8 MB /
  unsigned short* wqkv  = (unsigned short*)(ws + 41943040);    // 384 KB
  unsigned short* wproj = (unsigned short*)(ws + 42336256);    // 128 KB
  unsigned short* wfc1  = (unsigned short*)(ws + 42467328);    // 256 KB
  unsigned short* wfc2  = (unsigned short*)(ws + 42729472);    // 256 KB
  float*          bqkv  = (float*)(ws + 42991616);             // 3 KB
  float*          pe_buf= (float*)(ws + 42994688);             // ~97 KB
  unsigned short* attn_out = xln;
  unsigned short* yln   = (unsigned short*)q_buf;
  unsigned short* h1    = k_buf;

  cast_weights_kernel<<<2052, 256, 0, stream>>>(
      q_w, kv_w, proj_w, fc1_w, fc2_w, q_b, kv_b, wqkv, wproj, wfc1, wfc2, bqkv);
  pe_kernel<<<(kTAB * 8 + 255) / 256, 256, 0, stream>>>(pre_table, pe_w, pe_b, pe_buf);
  ln_bf16_kernel<<<kRowsTotal, 256, 0, stream>>>(feat, n1w, n1b, xln);

  mfma_gemm<0, 256><<<dim3(kRowsTotal / 128, 6), 256, 0, stream>>>(
      xln, wqkv, bqkv, q_buf, k_buf, v_buf, nullptr);

  attn_kernel<<<kRowsTotal / 4, 256, 0, stream>>>(
      q_buf, k_buf, v_buf, member_idx, pe_idx, cmask, pe_buf, blank_k, blank_v,
      attn_out);

  mfma_gemm<1, 256><<<dim3(kRowsTotal / 128, 2), 256, 0, stream>>>(
      attn_out, wproj, proj_b, out, nullptr, nullptr, feat);

  ln_bf16_kernel<<<kRowsTotal, 256, 0, stream>>>(out, n2w, n2b, yln);

  mfma_gemm<2, 256><<<dim3(kRowsTotal / 128, 4), 256, 0, stream>>>(
      yln, wfc1, fc1_b, h1, nullptr, nullptr, nullptr);

  mfma_gemm<3, 512><<<dim3(kRowsTotal / 128, 2), 256, 0, stream>>>(
      h1, wfc2, fc2_b, out, nullptr, nullptr, out);
}